// Round 21
// baseline (116.490 us; speedup 1.0000x reference)
//
#include <hip/hip_runtime.h>
#include <hip/hip_bf16.h>
#include <math.h>

// EulerCausalAttention on MI355X (gfx950).
// prep+wconv (fused) ; V-GEMM -> Vf (MFMA-fragment layout, R8's verified map) ;
// causal flash attention = R18's triple-buffer single-barrier loop, but V is
// read DIRECTLY from L2 in fragment layout (reg double-buffered, no V in LDS:
// LDS/step 96->64KB, LDS 48KB) ; out-GEMM (R18 triple-buffer, unchanged).

typedef __attribute__((ext_vector_type(8))) __bf16 bf16x8;
typedef __attribute__((ext_vector_type(4))) __bf16 bf16x4;
typedef __attribute__((ext_vector_type(4))) float f32x4;
typedef unsigned short ushort_t;
typedef unsigned int uint_t;

#define LUTC 651.8986469044033f       // 4096 / (2*pi)
#define ANG 0.0015339807878856412f    // 2*pi / 4096
#define QSCL 0.12751743590489435f     // log2(e) / sqrt(128)  (folded into Q)

__device__ __forceinline__ float fast_exp2(float x) {
#if __has_builtin(__builtin_amdgcn_exp2f)
  return __builtin_amdgcn_exp2f(x);
#else
  return exp2f(x);
#endif
}

__device__ __forceinline__ ushort_t f2bf(float f) {
  union { __bf16 b; ushort_t u; } cv;
  cv.b = (__bf16)f;
  return cv.u;
}

__device__ __forceinline__ void store8(ushort_t* p, const ushort_t v[8]) {
  uint4 u;
  u.x = (uint_t)v[0] | ((uint_t)v[1] << 16);
  u.y = (uint_t)v[2] | ((uint_t)v[3] << 16);
  u.z = (uint_t)v[4] | ((uint_t)v[5] << 16);
  u.w = (uint_t)v[6] | ((uint_t)v[7] << 16);
  *(uint4*)p = u;
}

__device__ __forceinline__ void gl_lds16(const void* g, void* l) {
  __builtin_amdgcn_global_load_lds(
      (__attribute__((address_space(1))) void*)(g),
      (__attribute__((address_space(3))) void*)(l),
      16, 0, 0);
}

// ------------------------------------------------------- prep + wconv -------
__global__ __launch_bounds__(256) void prep_kernel(
    const float* __restrict__ x, const float* __restrict__ wq, const float* __restrict__ bq,
    const float* __restrict__ wk, const float* __restrict__ bk,
    ushort_t* __restrict__ Qs, ushort_t* __restrict__ Ks, ushort_t* __restrict__ xb,
    const float* __restrict__ vw, const float* __restrict__ ow,
    ushort_t* __restrict__ vwb, ushort_t* __restrict__ owb)
{
  if (blockIdx.x >= 512) {
    int t = (blockIdx.x - 512) * 256 + threadIdx.x;   // 262144 threads
    const float* src;
    ushort_t* dst;
    int i;
    if (t < 131072) { src = vw; dst = vwb; i = t; }
    else            { src = ow; dst = owb; i = t - 131072; }
    const float4* p4 = (const float4*)(src + (size_t)i * 8);
    float4 a = p4[0], b = p4[1];
    float v[8] = {a.x, a.y, a.z, a.w, b.x, b.y, b.z, b.w};
    ushort_t o[8];
#pragma unroll
    for (int j = 0; j < 8; ++j) o[j] = f2bf(v[j]);
    store8(dst + (size_t)i * 8, o);
    return;
  }

  int t = blockIdx.x * 256 + threadIdx.x;   // 131072 threads
  int dm8 = t & 127;
  int g = t >> 7;                            // token group of 4
  int dm0 = dm8 * 8;
  int h = dm0 >> 6;

  float aq[8], cq[8], ak[8], ck[8];
#pragma unroll
  for (int j = 0; j < 8; ++j) {
    aq[j] = LUTC / (1.0f + fabsf(wq[dm0 + j]));
    cq[j] = LUTC * bq[dm0 + j];
    ak[j] = LUTC / (1.0f + fabsf(wk[dm0 + j]));
    ck[j] = LUTC * bk[dm0 + j];
  }
  for (int i = 0; i < 4; ++i) {
    int bs = g * 4 + i;
    int b = bs >> 11, s = bs & 2047;
    const float4* xp4 = (const float4*)(x + (size_t)bs * 1024 + dm0);
    float4 xa = xp4[0], xbv4 = xp4[1];
    float xv[8] = {xa.x, xa.y, xa.z, xa.w, xbv4.x, xbv4.y, xbv4.z, xbv4.w};
    ushort_t qc[8], qs[8], kc[8], ks[8], xo[8];
#pragma unroll
    for (int j = 0; j < 8; ++j) {
      int iq = ((int)rintf(fmaf(xv[j], aq[j], cq[j]))) & 4095;
      float sq, cqv;
      __sincosf((float)iq * ANG, &sq, &cqv);
      int ik = ((int)rintf(fmaf(xv[j], ak[j], ck[j]))) & 4095;
      float sk, ckv;
      __sincosf((float)ik * ANG, &sk, &ckv);
      qc[j] = f2bf(cqv * QSCL);
      qs[j] = f2bf(sq * QSCL);
      kc[j] = f2bf(ckv);
      ks[j] = f2bf(sk);
      xo[j] = f2bf(xv[j]);
    }
    size_t qb = ((size_t)(b * 16 + h) * 2048 + s) * 128 + (dm0 & 63);
    store8(Qs + qb, qc);        store8(Qs + qb + 64, qs);
    store8(Ks + qb, kc);        store8(Ks + qb + 64, ks);
    store8(xb + (size_t)bs * 1024 + dm0, xo);
  }
}

// ---------------------------------------------------------------- GEMM ------
// R18: tile 64x128, 4 waves, K-step 64, 512 blocks, triple-buffer 1-barrier.
// EPI 0: f32 C[m*N+n]. EPI 1: bf16 V-FRAGMENT layout (R8's verified mapping).
template <int EPI>
__global__ __launch_bounds__(256) void gemm_nt(
    const ushort_t* __restrict__ A, const ushort_t* __restrict__ B,
    float* __restrict__ Cf, ushort_t* __restrict__ Cb, int M, int N, int K)
{
  __shared__ __align__(16) ushort_t As[3][64 * 64];
  __shared__ __align__(16) ushort_t Bs[3][128 * 64];
  const int l = threadIdx.x & 63;
  const int w = threadIdx.x >> 6;
  const int g = l >> 4, lo = l & 15;
  const int mt = blockIdx.x % (M >> 6);
  const int nt = blockIdx.x / (M >> 6);
  const int m0 = mt << 6, n0 = nt << 7;

  const f32x4 zero4 = {0.f, 0.f, 0.f, 0.f};
  f32x4 acc[4][2];
#pragma unroll
  for (int i = 0; i < 4; ++i)
#pragma unroll
    for (int j = 0; j < 2; ++j) acc[i][j] = zero4;

  const int nk = K >> 6;

#define GEMM_STAGE(buf, k0_)                                                    \
  {                                                                             \
    int k0__ = (k0_);                                                           \
    _Pragma("unroll")                                                           \
    for (int i = 0; i < 2; ++i) {                                               \
      int ci = (w * 2 + i) * 64 + l;                                            \
      int r = ci >> 3, c = (ci & 7) ^ (r & 7);                                  \
      gl_lds16(A + (size_t)(m0 + r) * K + k0__ + c * 8, &As[buf][(w * 2 + i) * 512]); \
    }                                                                           \
    _Pragma("unroll")                                                           \
    for (int i = 0; i < 4; ++i) {                                               \
      int ci = (w * 4 + i) * 64 + l;                                            \
      int r = ci >> 3, c = (ci & 7) ^ (r & 7);                                  \
      gl_lds16(B + (size_t)(n0 + r) * K + k0__ + c * 8, &Bs[buf][(w * 4 + i) * 512]); \
    }                                                                           \
  }

  GEMM_STAGE(0, 0);
  GEMM_STAGE(1, 64);
  asm volatile("s_waitcnt vmcnt(6)" ::: "memory");
  __builtin_amdgcn_s_barrier();
  __builtin_amdgcn_sched_barrier(0);

  int rb = 0, wb = 2;
  for (int t = 0; t < nk; ++t) {
#pragma unroll
    for (int kk = 0; kk < 2; ++kk) {
      bf16x8 af[4], bfr[2];
#pragma unroll
      for (int mi = 0; mi < 4; ++mi) {
        int r = mi * 16 + lo;
        int ch = (g + 4 * kk) ^ (r & 7);
        af[mi] = *(const bf16x8*)&As[rb][r * 64 + ch * 8];
      }
#pragma unroll
      for (int ni = 0; ni < 2; ++ni) {
        int r = w * 32 + ni * 16 + lo;
        int ch = (g + 4 * kk) ^ (r & 7);
        bfr[ni] = *(const bf16x8*)&Bs[rb][r * 64 + ch * 8];
      }
#pragma unroll
      for (int mi = 0; mi < 4; ++mi)
#pragma unroll
        for (int ni = 0; ni < 2; ++ni)
          acc[mi][ni] = __builtin_amdgcn_mfma_f32_16x16x32_bf16(af[mi], bfr[ni], acc[mi][ni], 0, 0, 0);
    }
    __builtin_amdgcn_sched_barrier(0);
    if (t + 2 < nk) {
      GEMM_STAGE(wb, (t + 2) * 64);
      asm volatile("s_waitcnt lgkmcnt(0)" ::: "memory");
      asm volatile("s_waitcnt vmcnt(6)" ::: "memory");
    } else if (t + 1 < nk) {
      asm volatile("s_waitcnt lgkmcnt(0)" ::: "memory");
      asm volatile("s_waitcnt vmcnt(0)" ::: "memory");
    }
    if (t + 1 < nk) {
      __builtin_amdgcn_s_barrier();
      __builtin_amdgcn_sched_barrier(0);
    }
    rb = (rb == 2) ? 0 : rb + 1;
    wb = (wb == 2) ? 0 : wb + 1;
  }
#undef GEMM_STAGE

#pragma unroll
  for (int mi = 0; mi < 4; ++mi)
#pragma unroll
    for (int ni = 0; ni < 2; ++ni)
#pragma unroll
      for (int reg = 0; reg < 4; ++reg) {
        int row = m0 + mi * 16 + g * 4 + reg;
        int col = n0 + w * 32 + ni * 16 + lo;
        float v = acc[mi][ni][reg];
        if (EPI == 0) {
          Cf[(size_t)row * N + col] = v;
        } else {
          // V-fragment store (R8, verified): row = dmodel idx, col = token.
          int hh = row >> 6, dh = row & 63, nd = dh >> 4, lov = dh & 15;
          int bb = col >> 11, ss = col & 2047, kt = ss >> 6, sk = ss & 63;
          int kk2 = sk >> 5, gg = (sk >> 2) & 3, jj = ((sk >> 4) & 1) * 4 + (sk & 3);
          size_t o = ((((size_t)(bb * 16 + hh) * 32 + kt) * 8 + kk2 * 4 + nd) * 64
                      + gg * 16 + lov) * 8 + jj;
          Cb[o] = f2bf(v);
        }
      }
}

// ------------------------------------------------------------- attention ----
// R18 structure: 512 blocks x 256 threads, 4 waves x 32 q-rows, QBLK=128,
// KVBLK=64, balanced qt pairing, setprio, TRIPLE-buffer K + ONE barrier/step.
// V from GLOBAL in fragment layout (R8's verified read), reg double-buffered
// vfA/vfB via unroll-2 (nt always even). LDS = K only, 48KB.

template<bool MASKED>
__device__ __forceinline__ void attn_tile_v(
    const ushort_t* __restrict__ Kc, const bf16x8 (&vf)[8],
    const bf16x8 (&qf)[2][4], f32x4 (&accO)[2][4], f32x4 (&acc_l)[2],
    int kb, int qw, int lo, int g, const bf16x8& ones)
{
  const f32x4 zero4 = {0.f, 0.f, 0.f, 0.f};
  f32x4 sc[2][4];
#pragma unroll
  for (int qm = 0; qm < 2; ++qm)
#pragma unroll
    for (int ns = 0; ns < 4; ++ns) sc[qm][ns] = zero4;

  // S^T tile: lane holds S[q=qw+qm*16+lo][k=kb+ns*16+g*4+reg]
#pragma unroll
  for (int e = 0; e < 4; ++e) {
#pragma unroll
    for (int ns = 0; ns < 4; ++ns) {
      int kr = ns * 16 + lo;
      int cc = (g + 4 * e) ^ (kr & 7);
      bf16x8 kf = *(const bf16x8*)&Kc[kr * 128 + cc * 8];
#pragma unroll
      for (int qm = 0; qm < 2; ++qm)
        sc[qm][ns] = __builtin_amdgcn_mfma_f32_16x16x32_bf16(kf, qf[qm][e], sc[qm][ns], 0, 0, 0);
    }
  }

  // p = exp2(s), pack to PV A-fragments (registers only)
  bf16x8 pa[2][2];
#pragma unroll
  for (int qm = 0; qm < 2; ++qm) {
#pragma unroll
    for (int ns = 0; ns < 4; ++ns) {
#pragma unroll
      for (int reg = 0; reg < 4; ++reg) {
        float sv = sc[qm][ns][reg];
        if (MASKED) {
          int ka = kb + ns * 16 + g * 4 + reg;
          int qa = qw + qm * 16 + lo;
          sv = (ka <= qa) ? sv : -__builtin_inff();
        }
        pa[qm][ns >> 1][(ns & 1) * 4 + reg] = (__bf16)fast_exp2(sv);
      }
    }
  }

  // O += P V (V from registers) ; rowsum += P * ones
#pragma unroll
  for (int kk = 0; kk < 2; ++kk) {
#pragma unroll
    for (int nd = 0; nd < 4; ++nd) {
#pragma unroll
      for (int qm = 0; qm < 2; ++qm)
        accO[qm][nd] = __builtin_amdgcn_mfma_f32_16x16x32_bf16(pa[qm][kk], vf[kk * 4 + nd], accO[qm][nd], 0, 0, 0);
    }
#pragma unroll
    for (int qm = 0; qm < 2; ++qm)
      acc_l[qm] = __builtin_amdgcn_mfma_f32_16x16x32_bf16(pa[qm][kk], ones, acc_l[qm], 0, 0, 0);
  }
}

__global__ __launch_bounds__(256) void attn_kernel(
    const ushort_t* __restrict__ Qs, const ushort_t* __restrict__ Ks,
    const ushort_t* __restrict__ Vf, ushort_t* __restrict__ Ob)
{
  const int S = 2048;
  const int id = blockIdx.x;                 // 0..511
  const int bh = id & 31;
  const int qt = (id < 256) ? (15 - (id >> 5)) : ((id - 256) >> 5);
  const int l = threadIdx.x & 63;
  const int w = threadIdx.x >> 6;
  const int g = l >> 4, lo = l & 15;

  __shared__ __align__(16) ushort_t Kl[3][64 * 128];  // 3 x 16KB = 48KB

  const int q0b = qt * 128;
  const int qw = q0b + w * 32;
  const ushort_t* Kbase = Ks + (size_t)bh * S * 128;
  const ushort_t* Vg = Vf + (size_t)bh * 131072 + (size_t)l * 8;  // frag base

  bf16x8 ones;
#pragma unroll
  for (int j = 0; j < 8; ++j) ones[j] = (__bf16)1.0f;

  // Q fragments: qf[qm][e] = Q[qw+qm*16+lo][32e+8g .. +7]
  bf16x8 qf[2][4];
#pragma unroll
  for (int qm = 0; qm < 2; ++qm) {
    const ushort_t* qp = Qs + ((size_t)bh * S + qw + qm * 16 + lo) * 128 + 8 * g;
#pragma unroll
    for (int e = 0; e < 4; ++e) qf[qm][e] = *(const bf16x8*)(qp + 32 * e);
  }

  const f32x4 zero4 = {0.f, 0.f, 0.f, 0.f};
  f32x4 accO[2][4];
  f32x4 acc_l[2];
#pragma unroll
  for (int qm = 0; qm < 2; ++qm) {
    acc_l[qm] = zero4;
#pragma unroll
    for (int nd = 0; nd < 4; ++nd) accO[qm][nd] = zero4;
  }

  const int nt = 2 * qt + 2;   // always even, >= 2

#define ATTN_STAGE(buf, kb_)                                                    \
  {                                                                             \
    int kb__ = (kb_);                                                           \
    _Pragma("unroll")                                                           \
    for (int i = 0; i < 4; ++i) {                                               \
      int ci = (w * 4 + i) * 64 + l;                                            \
      int r = ci >> 4, c = (ci & 15) ^ (r & 7);                                 \
      gl_lds16(Kbase + (size_t)(kb__ + r) * 128 + c * 8, &Kl[buf][(w * 4 + i) * 512]); \
    }                                                                           \
  }

#define LOADV(dst, t_)                                                          \
  {                                                                             \
    const ushort_t* vp = Vg + (size_t)(t_) * 4096;                              \
    _Pragma("unroll")                                                           \
    for (int i = 0; i < 8; ++i) dst[i] = *(const bf16x8*)(vp + i * 512);        \
  }

  bf16x8 vfA[8], vfB[8];

  // prologue: K0, V0, K1 in that order -> vmcnt(4) leaves only K1 in flight
  ATTN_STAGE(0, 0);
  LOADV(vfA, 0);
  ATTN_STAGE(1, 64);
  asm volatile("s_waitcnt vmcnt(4)" ::: "memory");
  __builtin_amdgcn_s_barrier();
  __builtin_amdgcn_sched_barrier(0);

  int rb = 0;                     // t % 3
  int wb = 2;                     // (t+2) % 3

#define ATTN_STEP(T_, VFCUR_, VFNXT_)                                           \
  {                                                                             \
    const int t_ = (T_);                                                        \
    __builtin_amdgcn_s_setprio(1);                                              \
    if (t_ < 2 * qt)                                                            \
      attn_tile_v<false>(Kl[rb], VFCUR_, qf, accO, acc_l, t_ * 64, qw, lo, g, ones); \
    else                                                                        \
      attn_tile_v<true>(Kl[rb], VFCUR_, qf, accO, acc_l, t_ * 64, qw, lo, g, ones);  \
    __builtin_amdgcn_s_setprio(0);                                              \
    __builtin_amdgcn_sched_barrier(0);                                          \
    if (t_ + 1 < nt) LOADV(VFNXT_, t_ + 1);                                     \
    if (t_ + 2 < nt) {                                                          \
      ATTN_STAGE(wb, (t_ + 2) * 64);                                            \
      asm volatile("s_waitcnt lgkmcnt(0)" ::: "memory");                        \
      asm volatile("s_waitcnt vmcnt(4)" ::: "memory");  /* V(t+1)+K(t+1) done */ \
    } else if (t_ + 1 < nt) {                                                   \
      asm volatile("s_waitcnt lgkmcnt(0)" ::: "memory");                        \
      asm volatile("s_waitcnt vmcnt(0)" ::: "memory");                          \
    }                                                                           \
    if (t_ + 1 < nt) {                                                          \
      __builtin_amdgcn_s_barrier();                                             \
      __builtin_amdgcn_sched_barrier(0);                                        \
    }                                                                           \
    rb = (rb == 2) ? 0 : rb + 1;                                                \
    wb = (wb == 2) ? 0 : wb + 1;                                                \
  }

  for (int tt = 0; tt < nt; tt += 2) {
    ATTN_STEP(tt, vfA, vfB);
    ATTN_STEP(tt + 1, vfB, vfA);
  }
#undef ATTN_STEP
#undef LOADV
#undef ATTN_STAGE

  // normalize: acc_l layout == accO layout (row=(l>>4)*4+reg, replicated cols)
  float linv[2][4];
#pragma unroll
  for (int qm = 0; qm < 2; ++qm)
#pragma unroll
    for (int reg = 0; reg < 4; ++reg)
      linv[qm][reg] = 1.0f / acc_l[qm][reg];

  const int b = bh >> 4, h = bh & 15;
#pragma unroll
  for (int qm = 0; qm < 2; ++qm)
#pragma unroll
    for (int nd = 0; nd < 4; ++nd)
#pragma unroll
      for (int reg = 0; reg < 4; ++reg) {
        int q = qw + qm * 16 + g * 4 + reg;
        int d = nd * 16 + lo;
        Ob[((size_t)(b * 2048 + q)) * 1024 + h * 64 + d] = f2bf(accO[qm][nd][reg] * linv[qm][reg]);
      }
}

// ---------------------------------------------------------------- launch ----
extern "C" void kernel_launch(void* const* d_in, const int* in_sizes, int n_in,
                              void* d_out, int out_size, void* d_ws, size_t ws_size,
                              hipStream_t stream) {
  const float* x  = (const float*)d_in[0];
  const float* wq = (const float*)d_in[1];
  const float* bq = (const float*)d_in[2];
  const float* wk = (const float*)d_in[3];
  const float* bk = (const float*)d_in[4];
  const float* vw = (const float*)d_in[5];
  const float* ow = (const float*)d_in[6];
  float* out = (float*)d_out;

  char* ws = (char*)d_ws;
  ushort_t* Qs  = (ushort_t*)(ws);                      // 16 MB  [32][2048][128]
  ushort_t* Ksb = (ushort_t*)(ws + (16u << 20));        // 16 MB  [32][2048][128]
  ushort_t* Vfb = (ushort_t*)(ws + (32u << 20));        //  8 MB  frag [32][32][8][64][8]
  ushort_t* xbb = (ushort_t*)(ws + (40u << 20));        //  8 MB  [4096][1024]
  ushort_t* Obb = (ushort_t*)(ws + (48u << 20));        //  8 MB  [4096][1024]
  ushort_t* vwb = (ushort_t*)(ws + (56u << 20));        //  2 MB
  ushort_t* owb = (ushort_t*)(ws + (58u << 20));        //  2 MB

  prep_kernel<<<1536, 256, 0, stream>>>(x, wq, bq, wk, bk, Qs, Ksb, xbb,
                                        vw, ow, vwb, owb);
  gemm_nt<1><<<512, 256, 0, stream>>>(vwb, xbb, nullptr, Vfb, 1024, 4096, 1024);
  attn_kernel<<<512, 256, 0, stream>>>(Qs, Ksb, Vfb, Obb);
  gemm_nt<0><<<512, 256, 0, stream>>>(Obb, owb, out, nullptr, 4096, 1024, 1024);
}

// Round 22
// 94.094 us; speedup vs baseline: 1.2380x; 1.2380x over previous
//
#include <hip/hip_runtime.h>
#include <hip/hip_bf16.h>
#include <math.h>

// EulerCausalAttention on MI355X (gfx950).  ROUND-18 CONFIGURATION (best: 94.1us).
// prep+wconv (fused) ; V-GEMM -> Vt ; causal flash attention (4 waves x 32
// q-rows, KVBLK=64, balanced qt pairing, TRIPLE-buffer single-barrier k-loop,
// setprio) ; out-GEMM (triple-buffer).

typedef __attribute__((ext_vector_type(8))) __bf16 bf16x8;
typedef __attribute__((ext_vector_type(4))) __bf16 bf16x4;
typedef __attribute__((ext_vector_type(4))) float f32x4;
typedef unsigned short ushort_t;
typedef unsigned int uint_t;

#define LUTC 651.8986469044033f       // 4096 / (2*pi)
#define ANG 0.0015339807878856412f    // 2*pi / 4096
#define QSCL 0.12751743590489435f     // log2(e) / sqrt(128)  (folded into Q)

__device__ __forceinline__ float fast_exp2(float x) {
#if __has_builtin(__builtin_amdgcn_exp2f)
  return __builtin_amdgcn_exp2f(x);
#else
  return exp2f(x);
#endif
}

__device__ __forceinline__ ushort_t f2bf(float f) {
  union { __bf16 b; ushort_t u; } cv;
  cv.b = (__bf16)f;
  return cv.u;
}

__device__ __forceinline__ void store8(ushort_t* p, const ushort_t v[8]) {
  uint4 u;
  u.x = (uint_t)v[0] | ((uint_t)v[1] << 16);
  u.y = (uint_t)v[2] | ((uint_t)v[3] << 16);
  u.z = (uint_t)v[4] | ((uint_t)v[5] << 16);
  u.w = (uint_t)v[6] | ((uint_t)v[7] << 16);
  *(uint4*)p = u;
}

__device__ __forceinline__ void gl_lds16(const void* g, void* l) {
  __builtin_amdgcn_global_load_lds(
      (__attribute__((address_space(1))) void*)(g),
      (__attribute__((address_space(3))) void*)(l),
      16, 0, 0);
}

// ------------------------------------------------------- prep + wconv -------
__global__ __launch_bounds__(256) void prep_kernel(
    const float* __restrict__ x, const float* __restrict__ wq, const float* __restrict__ bq,
    const float* __restrict__ wk, const float* __restrict__ bk,
    ushort_t* __restrict__ Qs, ushort_t* __restrict__ Ks, ushort_t* __restrict__ xb,
    const float* __restrict__ vw, const float* __restrict__ ow,
    ushort_t* __restrict__ vwb, ushort_t* __restrict__ owb)
{
  if (blockIdx.x >= 512) {
    int t = (blockIdx.x - 512) * 256 + threadIdx.x;   // 262144 threads
    const float* src;
    ushort_t* dst;
    int i;
    if (t < 131072) { src = vw; dst = vwb; i = t; }
    else            { src = ow; dst = owb; i = t - 131072; }
    const float4* p4 = (const float4*)(src + (size_t)i * 8);
    float4 a = p4[0], b = p4[1];
    float v[8] = {a.x, a.y, a.z, a.w, b.x, b.y, b.z, b.w};
    ushort_t o[8];
#pragma unroll
    for (int j = 0; j < 8; ++j) o[j] = f2bf(v[j]);
    store8(dst + (size_t)i * 8, o);
    return;
  }

  int t = blockIdx.x * 256 + threadIdx.x;   // 131072 threads
  int dm8 = t & 127;
  int g = t >> 7;                            // token group of 4
  int dm0 = dm8 * 8;
  int h = dm0 >> 6;

  float aq[8], cq[8], ak[8], ck[8];
#pragma unroll
  for (int j = 0; j < 8; ++j) {
    aq[j] = LUTC / (1.0f + fabsf(wq[dm0 + j]));
    cq[j] = LUTC * bq[dm0 + j];
    ak[j] = LUTC / (1.0f + fabsf(wk[dm0 + j]));
    ck[j] = LUTC * bk[dm0 + j];
  }
  for (int i = 0; i < 4; ++i) {
    int bs = g * 4 + i;
    int b = bs >> 11, s = bs & 2047;
    const float4* xp4 = (const float4*)(x + (size_t)bs * 1024 + dm0);
    float4 xa = xp4[0], xbv4 = xp4[1];
    float xv[8] = {xa.x, xa.y, xa.z, xa.w, xbv4.x, xbv4.y, xbv4.z, xbv4.w};
    ushort_t qc[8], qs[8], kc[8], ks[8], xo[8];
#pragma unroll
    for (int j = 0; j < 8; ++j) {
      int iq = ((int)rintf(fmaf(xv[j], aq[j], cq[j]))) & 4095;
      float sq, cqv;
      __sincosf((float)iq * ANG, &sq, &cqv);
      int ik = ((int)rintf(fmaf(xv[j], ak[j], ck[j]))) & 4095;
      float sk, ckv;
      __sincosf((float)ik * ANG, &sk, &ckv);
      qc[j] = f2bf(cqv * QSCL);
      qs[j] = f2bf(sq * QSCL);
      kc[j] = f2bf(ckv);
      ks[j] = f2bf(sk);
      xo[j] = f2bf(xv[j]);
    }
    size_t qb = ((size_t)(b * 16 + h) * 2048 + s) * 128 + (dm0 & 63);
    store8(Qs + qb, qc);        store8(Qs + qb + 64, qs);
    store8(Ks + qb, kc);        store8(Ks + qb + 64, ks);
    store8(xb + (size_t)bs * 1024 + dm0, xo);
  }
}

// ---------------------------------------------------------------- GEMM ------
// Tile 64(m) x 128(n), 4 waves, K-step 64, 512 blocks = 2/CU.
// TRIPLE-buffer single-barrier pipeline.
template <int EPI>
__global__ __launch_bounds__(256) void gemm_nt(
    const ushort_t* __restrict__ A, const ushort_t* __restrict__ B,
    float* __restrict__ Cf, ushort_t* __restrict__ Cb, int M, int N, int K)
{
  __shared__ __align__(16) ushort_t As[3][64 * 64];    // 3 x 8KB
  __shared__ __align__(16) ushort_t Bs[3][128 * 64];   // 3 x 16KB (72KB total)
  const int l = threadIdx.x & 63;
  const int w = threadIdx.x >> 6;
  const int g = l >> 4, lo = l & 15;
  const int mt = blockIdx.x % (M >> 6);
  const int nt = blockIdx.x / (M >> 6);
  const int m0 = mt << 6, n0 = nt << 7;

  const f32x4 zero4 = {0.f, 0.f, 0.f, 0.f};
  f32x4 acc[4][2];
#pragma unroll
  for (int i = 0; i < 4; ++i)
#pragma unroll
    for (int j = 0; j < 2; ++j) acc[i][j] = zero4;

  const int nk = K >> 6;   // 16 for K=1024

#define GEMM_STAGE(buf, k0_)                                                    \
  {                                                                             \
    int k0__ = (k0_);                                                           \
    _Pragma("unroll")                                                           \
    for (int i = 0; i < 2; ++i) {                                               \
      int ci = (w * 2 + i) * 64 + l;                                            \
      int r = ci >> 3, c = (ci & 7) ^ (r & 7);                                  \
      gl_lds16(A + (size_t)(m0 + r) * K + k0__ + c * 8, &As[buf][(w * 2 + i) * 512]); \
    }                                                                           \
    _Pragma("unroll")                                                           \
    for (int i = 0; i < 4; ++i) {                                               \
      int ci = (w * 4 + i) * 64 + l;                                            \
      int r = ci >> 3, c = (ci & 7) ^ (r & 7);                                  \
      gl_lds16(B + (size_t)(n0 + r) * K + k0__ + c * 8, &Bs[buf][(w * 4 + i) * 512]); \
    }                                                                           \
  }

  GEMM_STAGE(0, 0);
  GEMM_STAGE(1, 64);
  asm volatile("s_waitcnt vmcnt(6)" ::: "memory");   // tile 0 landed
  __builtin_amdgcn_s_barrier();
  __builtin_amdgcn_sched_barrier(0);

  int rb = 0, wb = 2;
  for (int t = 0; t < nk; ++t) {
#pragma unroll
    for (int kk = 0; kk < 2; ++kk) {
      bf16x8 af[4], bfr[2];
#pragma unroll
      for (int mi = 0; mi < 4; ++mi) {
        int r = mi * 16 + lo;
        int ch = (g + 4 * kk) ^ (r & 7);
        af[mi] = *(const bf16x8*)&As[rb][r * 64 + ch * 8];
      }
#pragma unroll
      for (int ni = 0; ni < 2; ++ni) {
        int r = w * 32 + ni * 16 + lo;
        int ch = (g + 4 * kk) ^ (r & 7);
        bfr[ni] = *(const bf16x8*)&Bs[rb][r * 64 + ch * 8];
      }
#pragma unroll
      for (int mi = 0; mi < 4; ++mi)
#pragma unroll
        for (int ni = 0; ni < 2; ++ni)
          acc[mi][ni] = __builtin_amdgcn_mfma_f32_16x16x32_bf16(af[mi], bfr[ni], acc[mi][ni], 0, 0, 0);
    }
    __builtin_amdgcn_sched_barrier(0);
    if (t + 2 < nk) {
      GEMM_STAGE(wb, (t + 2) * 64);          // buffer last read at t-1: WAR-safe
      asm volatile("s_waitcnt lgkmcnt(0)" ::: "memory");  // own reads of rb done
      asm volatile("s_waitcnt vmcnt(6)" ::: "memory");    // stage(t+1) landed
    } else if (t + 1 < nk) {
      asm volatile("s_waitcnt lgkmcnt(0)" ::: "memory");
      asm volatile("s_waitcnt vmcnt(0)" ::: "memory");
    }
    if (t + 1 < nk) {
      __builtin_amdgcn_s_barrier();          // publish stage(t+1) completion
      __builtin_amdgcn_sched_barrier(0);
    }
    rb = (rb == 2) ? 0 : rb + 1;
    wb = (wb == 2) ? 0 : wb + 1;
  }
#undef GEMM_STAGE

#pragma unroll
  for (int mi = 0; mi < 4; ++mi)
#pragma unroll
    for (int ni = 0; ni < 2; ++ni)
#pragma unroll
      for (int reg = 0; reg < 4; ++reg) {
        int row = m0 + mi * 16 + g * 4 + reg;
        int col = n0 + w * 32 + ni * 16 + lo;
        float v = acc[mi][ni][reg];
        if (EPI == 0) {
          Cf[(size_t)row * N + col] = v;
        } else {
          size_t o = (size_t)(col >> 11) * (1024 * 2048) + (size_t)row * 2048 + (col & 2047);
          Cb[o] = f2bf(v);
        }
      }
}

// ------------------------------------------------------------- attention ----
// R18 (best): 512 blocks x 256 threads, 4 waves x 32 q-rows, QBLK=128,
// KVBLK=64, balanced qt pairing, setprio, TRIPLE-buffer + ONE barrier/step.

template<bool MASKED>
__device__ __forceinline__ void attn_tile(
    const ushort_t* __restrict__ Kc, const ushort_t* __restrict__ Vc,
    const bf16x8 (&qf)[2][4], f32x4 (&accO)[2][4], f32x4 (&acc_l)[2],
    int kb, int qw, int lo, int g, const bf16x8& ones)
{
  const f32x4 zero4 = {0.f, 0.f, 0.f, 0.f};
  f32x4 sc[2][4];
#pragma unroll
  for (int qm = 0; qm < 2; ++qm)
#pragma unroll
    for (int ns = 0; ns < 4; ++ns) sc[qm][ns] = zero4;

  // S^T tile: lane holds S[q=qw+qm*16+lo][k=kb+ns*16+g*4+reg]
#pragma unroll
  for (int e = 0; e < 4; ++e) {
#pragma unroll
    for (int ns = 0; ns < 4; ++ns) {
      int kr = ns * 16 + lo;
      int cc = (g + 4 * e) ^ (kr & 7);
      bf16x8 kf = *(const bf16x8*)&Kc[kr * 128 + cc * 8];
#pragma unroll
      for (int qm = 0; qm < 2; ++qm)
        sc[qm][ns] = __builtin_amdgcn_mfma_f32_16x16x32_bf16(kf, qf[qm][e], sc[qm][ns], 0, 0, 0);
    }
  }

  // p = exp2(s), pack to PV A-fragments (registers only)
  bf16x8 pa[2][2];
#pragma unroll
  for (int qm = 0; qm < 2; ++qm) {
#pragma unroll
    for (int ns = 0; ns < 4; ++ns) {
#pragma unroll
      for (int reg = 0; reg < 4; ++reg) {
        float sv = sc[qm][ns][reg];
        if (MASKED) {
          int ka = kb + ns * 16 + g * 4 + reg;
          int qa = qw + qm * 16 + lo;
          sv = (ka <= qa) ? sv : -__builtin_inff();
        }
        pa[qm][ns >> 1][(ns & 1) * 4 + reg] = (__bf16)fast_exp2(sv);
      }
    }
  }

  // O += P V ; rowsum += P * ones
#pragma unroll
  for (int kk = 0; kk < 2; ++kk) {
#pragma unroll
    for (int nd = 0; nd < 4; ++nd) {
      int vr = nd * 16 + lo;
      int h8 = (g & 1) * 4;
      int cc0 = (4 * kk + (g >> 1)) ^ (vr & 7);
      int cc1 = (4 * kk + 2 + (g >> 1)) ^ (vr & 7);
      union { bf16x8 v8; bf16x4 v4[2]; } u;
      u.v4[0] = *(const bf16x4*)&Vc[vr * 64 + cc0 * 8 + h8];
      u.v4[1] = *(const bf16x4*)&Vc[vr * 64 + cc1 * 8 + h8];
#pragma unroll
      for (int qm = 0; qm < 2; ++qm)
        accO[qm][nd] = __builtin_amdgcn_mfma_f32_16x16x32_bf16(pa[qm][kk], u.v8, accO[qm][nd], 0, 0, 0);
    }
#pragma unroll
    for (int qm = 0; qm < 2; ++qm)
      acc_l[qm] = __builtin_amdgcn_mfma_f32_16x16x32_bf16(pa[qm][kk], ones, acc_l[qm], 0, 0, 0);
  }
}

__global__ __launch_bounds__(256) void attn_kernel(
    const ushort_t* __restrict__ Qs, const ushort_t* __restrict__ Ks,
    const ushort_t* __restrict__ Vt, ushort_t* __restrict__ Ob)
{
  const int S = 2048;
  const int id = blockIdx.x;                 // 0..511
  const int bh = id & 31;
  const int qt = (id < 256) ? (15 - (id >> 5)) : ((id - 256) >> 5);
  const int l = threadIdx.x & 63;
  const int w = threadIdx.x >> 6;
  const int g = l >> 4, lo = l & 15;

  __shared__ __align__(16) ushort_t Kl[3][64 * 128];  // 3 x 16KB
  __shared__ __align__(16) ushort_t Vl[3][64 * 64];   // 3 x 8KB  (72KB total)

  const int q0b = qt * 128;
  const int qw = q0b + w * 32;
  const ushort_t* Kbase = Ks + (size_t)bh * S * 128;
  const ushort_t* Vbase = Vt + (size_t)bh * 64 * S;

  bf16x8 ones;
#pragma unroll
  for (int j = 0; j < 8; ++j) ones[j] = (__bf16)1.0f;

  // Q fragments: qf[qm][e] = Q[qw+qm*16+lo][32e+8g .. +7]
  bf16x8 qf[2][4];
#pragma unroll
  for (int qm = 0; qm < 2; ++qm) {
    const ushort_t* qp = Qs + ((size_t)bh * S + qw + qm * 16 + lo) * 128 + 8 * g;
#pragma unroll
    for (int e = 0; e < 4; ++e) qf[qm][e] = *(const bf16x8*)(qp + 32 * e);
  }

  const f32x4 zero4 = {0.f, 0.f, 0.f, 0.f};
  f32x4 accO[2][4];
  f32x4 acc_l[2];
#pragma unroll
  for (int qm = 0; qm < 2; ++qm) {
    acc_l[qm] = zero4;
#pragma unroll
    for (int nd = 0; nd < 4; ++nd) accO[qm][nd] = zero4;
  }

  const int nt = 2 * qt + 2;   // >= 2 always

#define ATTN_STAGE(buf, kb_)                                                    \
  {                                                                             \
    int kb__ = (kb_);                                                           \
    _Pragma("unroll")                                                           \
    for (int i = 0; i < 4; ++i) {                                               \
      int ci = (w * 4 + i) * 64 + l;                                            \
      int r = ci >> 4, c = (ci & 15) ^ (r & 7);                                 \
      gl_lds16(Kbase + (size_t)(kb__ + r) * 128 + c * 8, &Kl[buf][(w * 4 + i) * 512]); \
    }                                                                           \
    _Pragma("unroll")                                                           \
    for (int i = 0; i < 2; ++i) {                                               \
      int ci = (w * 2 + i) * 64 + l;                                            \
      int r = ci >> 3, c = (ci & 7) ^ (r & 7);                                  \
      gl_lds16(Vbase + (size_t)r * S + kb__ + c * 8, &Vl[buf][(w * 2 + i) * 512]); \
    }                                                                           \
  }

  // prologue: stage tiles 0,1 into buf 0,1; confirm tile 0 (6 newest in flight)
  ATTN_STAGE(0, 0);
  ATTN_STAGE(1, 64);
  asm volatile("s_waitcnt vmcnt(6)" ::: "memory");
  __builtin_amdgcn_s_barrier();
  __builtin_amdgcn_sched_barrier(0);

  int rb = 0;                     // t % 3
  int wb = 2;                     // (t+2) % 3
  for (int t = 0; t < nt; ++t) {
    __builtin_amdgcn_s_setprio(1);
    if (t < 2 * qt)
      attn_tile<false>(Kl[rb], Vl[rb], qf, accO, acc_l, t * 64, qw, lo, g, ones);
    else
      attn_tile<true>(Kl[rb], Vl[rb], qf, accO, acc_l, t * 64, qw, lo, g, ones);
    __builtin_amdgcn_s_setprio(0);
    __builtin_amdgcn_sched_barrier(0);
    if (t + 2 < nt) {
      ATTN_STAGE(wb, (t + 2) * 64);          // buffer last read at t-1: WAR-safe
      asm volatile("s_waitcnt lgkmcnt(0)" ::: "memory");  // own reads of rb done
      asm volatile("s_waitcnt vmcnt(6)" ::: "memory");    // own stage(t+1) landed
    } else if (t + 1 < nt) {
      asm volatile("s_waitcnt lgkmcnt(0)" ::: "memory");
      asm volatile("s_waitcnt vmcnt(0)" ::: "memory");    // tail: drain rest
    }
    if (t + 1 < nt) {
      __builtin_amdgcn_s_barrier();          // publish stage(t+1) completion
      __builtin_amdgcn_sched_barrier(0);
    }
    rb = (rb == 2) ? 0 : rb + 1;
    wb = (wb == 2) ? 0 : wb + 1;
  }
#undef ATTN_STAGE

  // normalize: acc_l layout == accO layout (row=(l>>4)*4+reg, replicated cols)
  float linv[2][4];
#pragma unroll
  for (int qm = 0; qm < 2; ++qm)
#pragma unroll
    for (int reg = 0; reg < 4; ++reg)
      linv[qm][reg] = 1.0f / acc_l[qm][reg];

  const int b = bh >> 4, h = bh & 15;
#pragma unroll
  for (int qm = 0; qm < 2; ++qm)
#pragma unroll
    for (int nd = 0; nd < 4; ++nd)
#pragma unroll
      for (int reg = 0; reg < 4; ++reg) {
        int q = qw + qm * 16 + g * 4 + reg;
        int d = nd * 16 + lo;
        Ob[((size_t)(b * 2048 + q)) * 1024 + h * 64 + d] = f2bf(accO[qm][nd][reg] * linv[qm][reg]);
      }
}

// ---------------------------------------------------------------- launch ----
extern "C" void kernel_launch(void* const* d_in, const int* in_sizes, int n_in,
                              void* d_out, int out_size, void* d_ws, size_t ws_size,
                              hipStream_t stream) {
  const float* x  = (const float*)d_in[0];
  const float* wq = (const float*)d_in[1];
  const float* bq = (const float*)d_in[2];
  const float* wk = (const float*)d_in[3];
  const float* bk = (const float*)d_in[4];
  const float* vw = (const float*)d_in[5];
  const float* ow = (const float*)d_in[6];
  float* out = (float*)d_out;

  char* ws = (char*)d_ws;
  ushort_t* Qs  = (ushort_t*)(ws);                      // 16 MB  [32][2048][128]
  ushort_t* Ksb = (ushort_t*)(ws + (16u << 20));        // 16 MB  [32][2048][128]
  ushort_t* Vtb = (ushort_t*)(ws + (32u << 20));        //  8 MB  [32][64][2048]
  ushort_t* xbb = (ushort_t*)(ws + (40u << 20));        //  8 MB  [4096][1024]
  ushort_t* Obb = (ushort_t*)(ws + (48u << 20));        //  8 MB  [4096][1024]
  ushort_t* vwb = (ushort_t*)(ws + (56u << 20));        //  2 MB
  ushort_t* owb = (ushort_t*)(ws + (58u << 20));        //  2 MB

  prep_kernel<<<1536, 256, 0, stream>>>(x, wq, bq, wk, bk, Qs, Ksb, xbb,
                                        vw, ow, vwb, owb);
  gemm_nt<1><<<512, 256, 0, stream>>>(vwb, xbb, nullptr, Vtb, 1024, 4096, 1024);
  attn_kernel<<<512, 256, 0, stream>>>(Qs, Ksb, Vtb, Obb);
  gemm_nt<0><<<512, 256, 0, stream>>>(Obb, owb, out, nullptr, 4096, 1024, 1024);
}